// Round 11
// baseline (144.782 us; speedup 1.0000x reference)
//
#include <hip/hip_runtime.h>

#define SC 20
#define HDIM 10
#define VOCAB 256
#define SENT VOCAB       // sentinel zero ctab row
#define CROWH 56         // ctab row stride in halves (112 B -> 8 bank classes)
#define XROW 72          // X row stride in halves (144 B -> 8 bank classes, 16B-aligned)
#define WAVES 8

typedef _Float16 f16;
typedef __attribute__((ext_vector_type(2))) _Float16 f16x2;
typedef __attribute__((ext_vector_type(8))) _Float16 f16x8;
typedef __attribute__((ext_vector_type(4))) float f32x4;

#if __has_builtin(__builtin_amdgcn_exp2f)
#define EXP2F(x) __builtin_amdgcn_exp2f(x)
#else
#define EXP2F(x) exp2f(x)
#endif
#if __has_builtin(__builtin_amdgcn_rcpf)
#define RCPF(x) __builtin_amdgcn_rcpf(x)
#else
#define RCPF(x) (1.0f / (x))
#endif
#define L2E 1.44269504088896340736f

__device__ __forceinline__ float fast_sig(float x) {
    return RCPF(1.0f + EXP2F(-x * L2E));
}
__device__ __forceinline__ float fast_tanh(float x) {
    float e = EXP2F(x * (2.0f * L2E));
    return 1.0f - 2.0f * RCPF(1.0f + e);
}
__device__ __forceinline__ unsigned pk(float a, float b) {
    f16x2 t = {(f16)a, (f16)b};
    return __builtin_bit_cast(unsigned, t);
}

__global__ __launch_bounds__(512, 6) void cnn_lstm_kernel(
    const int* __restrict__ inp, const float* __restrict__ emb,
    const float* __restrict__ k2, const float* __restrict__ k3,
    const float* __restrict__ k4,
    const float* __restrict__ wfw, const float* __restrict__ bfw,
    const float* __restrict__ wbw, const float* __restrict__ bbw,
    float* __restrict__ out)
{
    // ctab[v]: 4 age-slices x 12 conv feats (fp16) at 12-half boundaries.
    __shared__ __align__(16) f16 ctab[(VOCAB + 1) * CROWH];   // 28.8 KB
    // X rows: [slice0(12)|slice1(12)|slice2(12)|slice3(12)|h(10)|bias|0(13)]
    // K-layout k=12d+f for conv (A replicates W_x 4x), k=48+q for h, 58 bias.
    __shared__ __align__(16) f16 xbuf[WAVES][16][XROW];       // 18.4 KB

    const int tid  = threadIdx.x;
    const int lane = tid & 63;
    const int w    = tid >> 6;
    const int g    = lane >> 4;    // k-group / slice index / quad-group
    const int c16  = lane & 15;    // seq within wave / gate row for A

    // ---- build ctab: thread -> (vocab v = tid/2, two dlt slices) ------------
    {
        const int v  = tid >> 1;
        const int db = (tid & 1) * 2;
        float er[16];
        const float4* ep = (const float4*)(emb + v * 16);
        float4 e0 = ep[0], e1 = ep[1], e2 = ep[2], e3 = ep[3];
        er[0]=e0.x; er[1]=e0.y; er[2]=e0.z; er[3]=e0.w;
        er[4]=e1.x; er[5]=e1.y; er[6]=e1.z; er[7]=e1.w;
        er[8]=e2.x; er[9]=e2.y; er[10]=e2.z; er[11]=e2.w;
        er[12]=e3.x; er[13]=e3.y; er[14]=e3.z; er[15]=e3.w;

        #pragma unroll
        for (int dd = 0; dd < 2; ++dd) {
            const int dlt = db + dd;
            float o[12];
            #pragma unroll
            for (int f = 0; f < 12; ++f) o[f] = 0.0f;
            const int tap2 = 1 - dlt, tap3 = 2 - dlt, tap4 = 3 - dlt;
            if (tap2 >= 0) {
                #pragma unroll
                for (int e = 0; e < 16; ++e) {
                    const float x = er[e];
                    #pragma unroll
                    for (int f = 0; f < 3; ++f) o[f] += x * k2[(tap2 * 16 + e) * 3 + f];
                }
            }
            if (tap3 >= 0) {
                #pragma unroll
                for (int e = 0; e < 16; ++e) {
                    const float x = er[e];
                    #pragma unroll
                    for (int f = 0; f < 4; ++f) o[3 + f] += x * k3[(tap3 * 16 + e) * 4 + f];
                }
            }
            {
                #pragma unroll
                for (int e = 0; e < 16; ++e) {
                    const float x = er[e];
                    #pragma unroll
                    for (int f = 0; f < 5; ++f) o[7 + f] += x * k4[(tap4 * 16 + e) * 5 + f];
                }
            }
            uint2* dst = (uint2*)&ctab[v * CROWH + 12 * dlt];
            dst[0] = make_uint2(pk(o[0], o[1]), pk(o[2], o[3]));
            dst[1] = make_uint2(pk(o[4], o[5]), pk(o[6], o[7]));
            dst[2] = make_uint2(pk(o[8], o[9]), pk(o[10], o[11]));
        }
    }
    if (tid < 12) ((uint2*)&ctab[SENT * CROWH])[tid] = make_uint2(0u, 0u);

    // init h/bias/pad region (halves 48..63) of own wave's rows
    if (g == 0) {
        uint4* hr = (uint4*)&xbuf[w][c16][48];
        hr[0] = make_uint4(0u, 0u, 0u, 0u);                     // h0..h7 = 0
        hr[1] = make_uint4(0u, pk(1.0f, 0.0f), 0u, 0u);         // h8,h9=0, bias=1, pad=0
    }
    __syncthreads();

    // ---- per-(seq, dir): wave = 16 seqs ------------------------------------
    const int dir = blockIdx.x >> 9;               // 1024 blocks: 0..511 fw
    const bool fw = (dir == 0);
    const int nbase = (blockIdx.x & 511) * 128 + w * 16;
    const int n = nbase + c16;
    const int* inp_n = inp + n * SC;
    const float* Wm = fw ? wfw : wbw;
    const float* Bv = fw ? bfw : bbw;

    // A-frags (loaded once): gate-in-tile = c16 = 4*qg + r; unit Lq per tile;
    // k rows: 0..47 -> W_x[k%12] (replicated per age), 48..57 -> W_h, 58 bias.
    f16x8 afr[3][2];
    {
        const int qg = c16 >> 2, r = c16 & 3;
        #pragma unroll
        for (int mg = 0; mg < 3; ++mg) {
            const int Lq = (mg == 0) ? 2 * qg : (mg == 1) ? (2 * qg + 1) : (8 + qg);
            const bool valid = (Lq < HDIM);
            const int lcol = r * HDIM + Lq;
            #pragma unroll
            for (int seg = 0; seg < 2; ++seg)
                #pragma unroll
                for (int i = 0; i < 8; ++i) {
                    const int k = 32 * seg + 8 * g + i;
                    float val = 0.0f;
                    if (valid) {
                        if (k < 48)       val = Wm[(k % 12) * 40 + lcol];
                        else if (k < 58)  val = Wm[(k - 36) * 40 + lcol];  // h rows 12..21
                        else if (k == 58) val = Bv[lcol];
                    }
                    afr[mg][seg][i] = (f16)val;
                }
        }
    }

    auto chload = [&](int q) -> int {
        return ((unsigned)q < (unsigned)SC) ? inp_n[q] : SENT;
    };

    // prologue: every lane gathers slice g of x(0) for its seq
    {
        const int a0 = chload((fw ? 0 : SC - 1) - g);
        const uint2* src = (const uint2*)&ctab[a0 * CROWH + 12 * g];
        uint2 p0 = src[0], p1 = src[1], p2 = src[2];
        uint2* dst = (uint2*)&xbuf[w][c16][12 * g];
        dst[0] = p0; dst[1] = p1; dst[2] = p2;
    }
    // char for iter-0's gather of x(1)
    int a = chload(fw ? (1 - g) : (SC - 2 - g));

    float creg[3] = {0.0f, 0.0f, 0.0f};
    float hreg[3] = {0.0f, 0.0f, 0.0f};
    const f32x4 zero4 = {0.0f, 0.0f, 0.0f, 0.0f};

    #pragma unroll 1
    for (int t = 0; t < SC; ++t) {
        // 1. B-frags of x(t) (x/h committed by prior program-order LDS writes)
        f16x8 bf0 = *(const f16x8*)&xbuf[w][c16][8 * g];
        f16x8 bf1 = *(const f16x8*)&xbuf[w][c16][32 + 8 * g];
        __builtin_amdgcn_sched_barrier(0);

        // 2. gather slice g of x(t+1) (latency hides under MFMA+combine)
        const bool dog = (t < SC - 1);
        uint2 p0, p1, p2;
        if (dog) {
            const uint2* src = (const uint2*)&ctab[a * CROWH + 12 * g];
            p0 = src[0]; p1 = src[1]; p2 = src[2];
        }
        // prefetch char for x(t+2)
        a = chload(fw ? (t + 2 - g) : (SC - 3 - t - g));
        __builtin_amdgcn_sched_barrier(0);

        // 3. 6 MFMAs: Z^T = W_perm^T . X^T, K=64 in two chained segments
        f32x4 acc0, acc1, acc2;
        acc0 = __builtin_amdgcn_mfma_f32_16x16x32_f16(afr[0][0], bf0, zero4, 0, 0, 0);
        acc1 = __builtin_amdgcn_mfma_f32_16x16x32_f16(afr[1][0], bf0, zero4, 0, 0, 0);
        acc2 = __builtin_amdgcn_mfma_f32_16x16x32_f16(afr[2][0], bf0, zero4, 0, 0, 0);
        acc0 = __builtin_amdgcn_mfma_f32_16x16x32_f16(afr[0][1], bf1, acc0, 0, 0, 0);
        acc1 = __builtin_amdgcn_mfma_f32_16x16x32_f16(afr[1][1], bf1, acc1, 0, 0, 0);
        acc2 = __builtin_amdgcn_mfma_f32_16x16x32_f16(afr[2][1], bf1, acc2, 0, 0, 0);
        __builtin_amdgcn_sched_barrier(0);

        // 4. combine: lane owns units {2g, 2g+1, 8+g} of seq c16
        {
            const float ij0 = fast_sig(acc0[0]) * fast_tanh(acc0[1]);
            creg[0] = fast_sig(acc0[2] + 1.0f) * creg[0] + ij0;
            hreg[0] = fast_sig(acc0[3]) * fast_tanh(creg[0]);
            const float ij1 = fast_sig(acc1[0]) * fast_tanh(acc1[1]);
            creg[1] = fast_sig(acc1[2] + 1.0f) * creg[1] + ij1;
            hreg[1] = fast_sig(acc1[3]) * fast_tanh(creg[1]);
            const float ij2 = fast_sig(acc2[0]) * fast_tanh(acc2[1]);
            creg[2] = fast_sig(acc2[2] + 1.0f) * creg[2] + ij2;
            hreg[2] = fast_sig(acc2[3]) * fast_tanh(creg[2]);
        }
        // 5. h-writes (units 2g,2g+1 packed; 8+g for g<2)
        *(unsigned*)&xbuf[w][c16][48 + 2 * g] = pk(hreg[0], hreg[1]);
        if (g < 2) xbuf[w][c16][56 + g] = (f16)hreg[2];
        // 6. commit slice of x(t+1) (after step-1 reads: WAR-safe, in-order)
        if (dog) {
            uint2* dst = (uint2*)&xbuf[w][c16][12 * g];
            dst[0] = p0; dst[1] = p1; dst[2] = p2;
        }
        __builtin_amdgcn_sched_barrier(0);
    }

    // ---- output: units {2g,2g+1} paired, {8+g} masked ----------------------
    {
        float2 hv;
        hv.x = hreg[0];
        hv.y = hreg[1];
        *(float2*)&out[n * (2 * HDIM) + dir * HDIM + 2 * g] = hv;
        if (g < 2) out[n * (2 * HDIM) + dir * HDIM + 8 + g] = hreg[2];
    }
}

extern "C" void kernel_launch(void* const* d_in, const int* in_sizes, int n_in,
                              void* d_out, int out_size, void* d_ws, size_t ws_size,
                              hipStream_t stream) {
    const int*   inp = (const int*)d_in[0];
    const float* emb = (const float*)d_in[1];
    const float* k2  = (const float*)d_in[2];
    const float* k3  = (const float*)d_in[3];
    const float* k4  = (const float*)d_in[4];
    const float* wfw = (const float*)d_in[5];
    const float* bfw = (const float*)d_in[6];
    const float* wbw = (const float*)d_in[7];
    const float* bbw = (const float*)d_in[8];
    float* out = (float*)d_out;

    // 1024 blocks x 512 threads: 8 waves/block, 16 seqs/wave, 4 lanes/seq.
    cnn_lstm_kernel<<<dim3(1024), dim3(512), 0, stream>>>(
        inp, emb, k2, k3, k4, wfw, bfw, wbw, bbw, out);
}

// Round 12
// 52.672 us; speedup vs baseline: 2.7488x; 2.7488x over previous
//
#include <hip/hip_runtime.h>

#define SC 20
#define HDIM 10
#define VOCAB 256
#define SENT VOCAB       // sentinel zero ctab row
#define CROWH 56         // ctab row stride in halves (112 B -> 8 bank classes)
#define XROW 24          // xbuf row stride in halves (48 B)
#define WAVES 4

typedef _Float16 f16;
typedef __attribute__((ext_vector_type(2))) _Float16 f16x2;
typedef __attribute__((ext_vector_type(8))) _Float16 f16x8;
typedef __attribute__((ext_vector_type(4))) float f32x4;

#if __has_builtin(__builtin_amdgcn_exp2f)
#define EXP2F(x) __builtin_amdgcn_exp2f(x)
#else
#define EXP2F(x) exp2f(x)
#endif
#if __has_builtin(__builtin_amdgcn_rcpf)
#define RCPF(x) __builtin_amdgcn_rcpf(x)
#else
#define RCPF(x) (1.0f / (x))
#endif
#define L2E 1.44269504088896340736f

__device__ __forceinline__ f16x2 bc2(unsigned u) { return __builtin_bit_cast(f16x2, u); }
__device__ __forceinline__ unsigned bcu(f16x2 v) { return __builtin_bit_cast(unsigned, v); }
__device__ __forceinline__ unsigned pk(float a, float b) {
    f16x2 t = {(f16)a, (f16)b};
    return __builtin_bit_cast(unsigned, t);
}

// gather issue: 10 LDS reads of 4 age-slices (one seq)
#define G_ISSUE                                                         \
    {   const f16* q0 = &ctab[a0 * CROWH];                              \
        g0a = *(const uint4*)q0;  g0b = *(const uint2*)(q0 + 8);        \
        const f16* q1 = &ctab[a1 * CROWH + 12];                         \
        g1a = *(const uint2*)q1;  g1b = *(const uint2*)(q1 + 4);        \
        g1c = *(const uint2*)(q1 + 8);                                  \
        const f16* q2 = &ctab[a2 * CROWH + 24];                         \
        g2a = *(const uint4*)q2;  g2b = *(const uint2*)(q2 + 8);        \
        const f16* q3 = &ctab[a3 * CROWH + 36];                         \
        g3a = *(const uint2*)q3;  g3b = *(const uint2*)(q3 + 4);        \
        g3c = *(const uint2*)(q3 + 8); }

// gather sum: 18 packed f16 adds -> xg0..5 (12 conv feats)
#define G_SUM                                                           \
    {   f16x2 s0 = bc2(g0a.x) + bc2(g1a.x) + bc2(g2a.x) + bc2(g3a.x);  \
        f16x2 s1 = bc2(g0a.y) + bc2(g1a.y) + bc2(g2a.y) + bc2(g3a.y);  \
        f16x2 s2 = bc2(g0a.z) + bc2(g1b.x) + bc2(g2a.z) + bc2(g3b.x);  \
        f16x2 s3 = bc2(g0a.w) + bc2(g1b.y) + bc2(g2a.w) + bc2(g3b.y);  \
        f16x2 s4 = bc2(g0b.x) + bc2(g1c.x) + bc2(g2b.x) + bc2(g3c.x);  \
        f16x2 s5 = bc2(g0b.y) + bc2(g1c.y) + bc2(g2b.y) + bc2(g3c.y);  \
        xg0 = bcu(s0); xg1 = bcu(s1); xg2 = bcu(s2);                   \
        xg3 = bcu(s3); xg4 = bcu(s4); xg5 = bcu(s5); }

// advance rolling ages by 2 processing steps
#define G_ADV                                                           \
    if (fw) { a3 = a1; a2 = a0; a1 = chload(pp + 1); a0 = chload(pp + 2); pp += 2; } \
    else    { a0 = a2; a1 = a3; a2 = chload(pp - 4); a3 = chload(pp - 5); pp -= 2; }

#define X_COMMIT                                                        \
    {   f16* xr = &xbuf[w][s][0];                                       \
        *(uint4*)xr = make_uint4(xg0, xg1, xg2, xg3);                   \
        *(uint2*)(xr + 8) = make_uint2(xg4, xg5); }

// combine 3 units: gate args arrive PRE-SCALED from the MFMA
// (i,f,o cols x(-L2E), j col x(-2L2E), forget bias+1 folded).
__device__ __forceinline__ void combine3(const f32x4* acc, float* cr, float* hr) {
    #pragma unroll
    for (int mg = 0; mg < 3; ++mg) {
        const f32x4 z = acc[mg];
        const float E0 = EXP2F(z[0]);                       // e^-zi
        const float E1 = EXP2F(z[1]);                       // e^-2zj
        const float R  = RCPF((1.0f + E0) * (1.0f + E1));
        const float ij = (1.0f - E1) * R;                   // sig(zi)*tanh(zj)
        const float E2 = EXP2F(z[2]);                       // e^-(zf+1)
        const float E3 = EXP2F(z[3]);                       // e^-zo
        const float R2 = RCPF((1.0f + E2) * (1.0f + E3));
        const float fg = (1.0f + E3) * R2;                  // sig(zf+1)
        const float og = (1.0f + E2) * R2;                  // sig(zo)
        cr[mg] = fg * cr[mg] + ij;
        const float u  = EXP2F(-2.0f * L2E * cr[mg]);
        const float th = (1.0f - u) * RCPF(1.0f + u);       // tanh(c)
        hr[mg] = og * th;
    }
}

__global__ __launch_bounds__(256, 4) void cnn_lstm_kernel(
    const int* __restrict__ inp, const float* __restrict__ emb,
    const float* __restrict__ k2, const float* __restrict__ k3,
    const float* __restrict__ k4,
    const float* __restrict__ wfw, const float* __restrict__ bfw,
    const float* __restrict__ wbw, const float* __restrict__ bbw,
    float* __restrict__ out)
{
    __shared__ __align__(16) f16 ctab[(VOCAB + 1) * CROWH];   // 28.8 KB
    __shared__ __align__(16) f16 xbuf[WAVES][33][XROW];       // 6.3 KB

    const int tid  = threadIdx.x;
    const int lane = tid & 63;
    const int w    = tid >> 6;
    const int g    = lane >> 4;     // k-group
    const int c16  = lane & 15;
    const int p    = lane >> 5;     // parity role (0/1)
    const int s    = lane & 31;     // owned seq within wave

    // ---- build ctab: thread v = tid handles one vocab row ------------------
    {
        float er[16];
        const float4* ep = (const float4*)(emb + tid * 16);
        float4 e0 = ep[0], e1 = ep[1], e2 = ep[2], e3 = ep[3];
        er[0]=e0.x; er[1]=e0.y; er[2]=e0.z; er[3]=e0.w;
        er[4]=e1.x; er[5]=e1.y; er[6]=e1.z; er[7]=e1.w;
        er[8]=e2.x; er[9]=e2.y; er[10]=e2.z; er[11]=e2.w;
        er[12]=e3.x; er[13]=e3.y; er[14]=e3.z; er[15]=e3.w;

        unsigned wd[24];
        #pragma unroll
        for (int dlt = 0; dlt < 4; ++dlt) {
            float o[12];
            #pragma unroll
            for (int f = 0; f < 12; ++f) o[f] = 0.0f;
            const int tap2 = 1 - dlt, tap3 = 2 - dlt, tap4 = 3 - dlt;
            if (tap2 >= 0) {
                #pragma unroll
                for (int e = 0; e < 16; ++e) {
                    const float x = er[e];
                    #pragma unroll
                    for (int f = 0; f < 3; ++f) o[f] += x * k2[(tap2 * 16 + e) * 3 + f];
                }
            }
            if (tap3 >= 0) {
                #pragma unroll
                for (int e = 0; e < 16; ++e) {
                    const float x = er[e];
                    #pragma unroll
                    for (int f = 0; f < 4; ++f) o[3 + f] += x * k3[(tap3 * 16 + e) * 4 + f];
                }
            }
            {
                #pragma unroll
                for (int e = 0; e < 16; ++e) {
                    const float x = er[e];
                    #pragma unroll
                    for (int f = 0; f < 5; ++f) o[7 + f] += x * k4[(tap4 * 16 + e) * 5 + f];
                }
            }
            #pragma unroll
            for (int k = 0; k < 6; ++k) wd[6 * dlt + k] = pk(o[2 * k], o[2 * k + 1]);
        }
        uint4* dst = (uint4*)&ctab[tid * CROWH];
        #pragma unroll
        for (int j = 0; j < 6; ++j)
            dst[j] = make_uint4(wd[4 * j], wd[4 * j + 1], wd[4 * j + 2], wd[4 * j + 3]);
    }
    if (tid < 6) ((uint4*)&ctab[SENT * CROWH])[tid] = make_uint4(0, 0, 0, 0);

    // ---- per-wave init ------------------------------------------------------
    const int dir   = blockIdx.x >> 9;             // 1024 blocks: 0..511 fw
    const bool fw   = (dir == 0);
    const int nbase = (blockIdx.x & 511) * 128 + w * 32;
    const int* inp_s = inp + (nbase + s) * SC;
    const float* Wm = fw ? wfw : wbw;
    const float* Bv = fw ? bfw : bbw;

    // A-frags, loaded once, PRE-SCALED: phys gate 16mg+4q+r = part r of quad
    // Lq = {2q,2q+1,8+q}[mg]; cols scaled by -L2E (j part by -2L2E); forget
    // bias +1 folded into the k=22 bias row.
    f16x8 afr[3];
    {
        const int qg = c16 >> 2, r = c16 & 3;
        const float sc = (r == 1) ? (-2.0f * L2E) : (-L2E);
        #pragma unroll
        for (int mg = 0; mg < 3; ++mg) {
            const int Lq = (mg == 0) ? 2 * qg : (mg == 1) ? (2 * qg + 1) : (8 + qg);
            const bool valid = (Lq < HDIM);
            const int lcol = r * HDIM + Lq;
            #pragma unroll
            for (int i = 0; i < 8; ++i) {
                const int kk = 8 * g + i;
                float val = 0.0f;
                if (valid) {
                    if (kk < 22)       val = Wm[kk * 40 + lcol];
                    else if (kk == 22) val = Bv[lcol] + ((r == 2) ? 1.0f : 0.0f);
                    val *= sc;
                }
                afr[mg][i] = (f16)val;
            }
        }
    }

    // init own X row h-part (h=0, bias 1.0 at half 22) and the junk row
    if (p == 0) {
        f16* xr = &xbuf[w][s][0];
        *(uint2*)(xr + 12) = make_uint2(0u, 0u);
        *(uint2*)(xr + 16) = make_uint2(0u, 0u);
        *(uint2*)(xr + 20) = make_uint2(0u, pk(1.0f, 0.0f));
    }
    if (lane == 0) {
        uint4* jr = (uint4*)&xbuf[w][32][0];
        jr[0] = make_uint4(0, 0, 0, 0);
        jr[1] = make_uint4(0, 0, 0, 0);
        jr[2] = make_uint4(0, 0, 0, 0);
    }
    __syncthreads();

    auto chload = [&](int q) -> int {
        return ((unsigned)q < (unsigned)SC) ? inp_s[q] : SENT;
    };

    // rolling ages; lane's first gather target = x(p)
    int pp = fw ? p : (SC - 1 - p);
    int a0 = chload(pp), a1 = chload(pp - 1), a2 = chload(pp - 2), a3 = chload(pp - 3);

    unsigned xg0, xg1, xg2, xg3, xg4, xg5;
    uint4 g0a, g2a;
    uint2 g0b, g1a, g1b, g1c, g2b, g3a, g3b, g3c;

    // prologue: p0 gathers+commits x(0); p1 gathers x(1) (sum deferred)
    if (p == 0) {
        G_ISSUE
        G_SUM
        X_COMMIT
        G_ADV                    // p0 next target: x(2)
    } else {
        G_ISSUE
        G_ADV                    // p1 next target: x(3); x(1) payload held
    }

    float creg0[3] = {0.f, 0.f, 0.f}, hreg0[3] = {0.f, 0.f, 0.f};
    float creg1[3] = {0.f, 0.f, 0.f}, hreg1[3] = {0.f, 0.f, 0.f};
    const f32x4 zero4 = {0.0f, 0.0f, 0.0f, 0.0f};

    // prologue MFMA for group0 (seqs c16) at t=0
    f32x4 acc0[3], acc1[3];
    f16x8 bf0 = *(const f16x8*)&xbuf[w][c16][8 * g];
    #pragma unroll
    for (int mg = 0; mg < 3; ++mg)
        acc0[mg] = __builtin_amdgcn_mfma_f32_16x16x32_f16(afr[mg], bf0, zero4, 0, 0, 0);
    f16x8 bf1 = *(const f16x8*)&xbuf[w][16 + c16][8 * g];
    __builtin_amdgcn_sched_barrier(0);

    #pragma unroll 1
    for (int t = 0; t < SC; ++t) {
        // 1. MFMA group1 (Z of seqs 16+c16 at t); latency hidden by step 2
        #pragma unroll
        for (int mg = 0; mg < 3; ++mg)
            acc1[mg] = __builtin_amdgcn_mfma_f32_16x16x32_f16(afr[mg], bf1, zero4, 0, 0, 0);
        __builtin_amdgcn_sched_barrier(0);

        // 2. combine group0 (t); write h(g0,t)
        combine3(acc0, creg0, hreg0);
        {
            f16* xr = &xbuf[w][c16][0];
            *(unsigned*)(xr + 12 + 2 * g) = pk(hreg0[0], hreg0[1]);
            if (g < 2) xr[20 + g] = (f16)hreg0[2];
        }
        // 3. committer lanes finish + commit x(t+1)
        if (t < SC - 1 && p == ((t + 1) & 1)) {
            G_SUM
            X_COMMIT
        }
        __builtin_amdgcn_sched_barrier(0);

        // 4. read bf0 for t+1 (sees x(t+1) + h(g0,t)); latency hidden by 5
        bf0 = *(const f16x8*)&xbuf[w][c16][8 * g];
        __builtin_amdgcn_sched_barrier(0);

        // 5. combine group1 (t); write h(g1,t)
        combine3(acc1, creg1, hreg1);
        {
            f16* xr = &xbuf[w][16 + c16][0];
            *(unsigned*)(xr + 12 + 2 * g) = pk(hreg1[0], hreg1[1]);
            if (g < 2) xr[20 + g] = (f16)hreg1[2];
        }
        if (t == SC - 1) break;
        __builtin_amdgcn_sched_barrier(0);

        // 6. MFMA group0 for t+1
        #pragma unroll
        for (int mg = 0; mg < 3; ++mg)
            acc0[mg] = __builtin_amdgcn_mfma_f32_16x16x32_f16(afr[mg], bf0, zero4, 0, 0, 0);

        // 7. read bf1 for t+1 (sees h(g1,t) from step 5)
        bf1 = *(const f16x8*)&xbuf[w][16 + c16][8 * g];

        // 8. gatherer lanes issue reads for x(t+2)
        if (t < SC - 2 && p == (t & 1)) {
            G_ISSUE
            G_ADV
        }
        __builtin_amdgcn_sched_barrier(0);
    }

    // ---- output: lane owns units {2g,2g+1,8+g} of seqs {c16, 16+c16} -------
    {
        const int n0 = nbase + c16;
        float2 hv0; hv0.x = hreg0[0]; hv0.y = hreg0[1];
        *(float2*)&out[n0 * (2 * HDIM) + dir * HDIM + 2 * g] = hv0;
        if (g < 2) out[n0 * (2 * HDIM) + dir * HDIM + 8 + g] = hreg0[2];
        const int n1 = nbase + 16 + c16;
        float2 hv1; hv1.x = hreg1[0]; hv1.y = hreg1[1];
        *(float2*)&out[n1 * (2 * HDIM) + dir * HDIM + 2 * g] = hv1;
        if (g < 2) out[n1 * (2 * HDIM) + dir * HDIM + 8 + g] = hreg1[2];
    }
}

extern "C" void kernel_launch(void* const* d_in, const int* in_sizes, int n_in,
                              void* d_out, int out_size, void* d_ws, size_t ws_size,
                              hipStream_t stream) {
    const int*   inp = (const int*)d_in[0];
    const float* emb = (const float*)d_in[1];
    const float* k2  = (const float*)d_in[2];
    const float* k3  = (const float*)d_in[3];
    const float* k4  = (const float*)d_in[4];
    const float* wfw = (const float*)d_in[5];
    const float* bfw = (const float*)d_in[6];
    const float* wbw = (const float*)d_in[7];
    const float* bbw = (const float*)d_in[8];
    float* out = (float*)d_out;

    // 1024 blocks x 256 threads: 32 seqs/wave, staggered two-group pipeline.
    cnn_lstm_kernel<<<dim3(1024), dim3(256), 0, stream>>>(
        inp, emb, k2, k3, k4, wfw, bfw, wbw, bbw, out);
}